// Round 1
// baseline (212.752 us; speedup 1.0000x reference)
//
#include <hip/hip_runtime.h>
#include <hip/hip_bf16.h>

#define C_CLASSES 8192
#define M_ROWS    65536
#define B_ROWS    256
#define D_DIM     2048
#define TEMP_INV  20.0f   // 1 / 0.05

typedef __attribute__((ext_vector_type(8))) short short8;   // 8 bf16 (4 VGPRs)
typedef __attribute__((ext_vector_type(4))) float f32x4;    // MFMA accumulator

static __device__ __forceinline__ unsigned short f2bf(float x) {
    __hip_bfloat16 h = __float2bfloat16(x);
    return *reinterpret_cast<unsigned short*>(&h);
}

// ---------------- histogram of labels ----------------
__global__ void k_hist(const int* __restrict__ labels, int* __restrict__ counts) {
    int m = blockIdx.x * 256 + threadIdx.x;   // grid sized exactly M/256
    atomicAdd(&counts[labels[m]], 1);
}

// ---------------- exclusive scan over 8192 counts (1 block) ----------------
__global__ __launch_bounds__(256) void k_scan(const int* __restrict__ counts,
                                              int* __restrict__ offsets,
                                              int* __restrict__ cursor) {
    __shared__ int part[256];
    int t = threadIdx.x;
    int local[32];
    int s = 0;
    #pragma unroll
    for (int i = 0; i < 32; ++i) { local[i] = counts[t * 32 + i]; s += local[i]; }
    part[t] = s;
    __syncthreads();
    if (t == 0) {
        int acc = 0;
        for (int i = 0; i < 256; ++i) { int v = part[i]; part[i] = acc; acc += v; }
    }
    __syncthreads();
    int off = part[t];
    #pragma unroll
    for (int i = 0; i < 32; ++i) {
        offsets[t * 32 + i] = off;
        cursor[t * 32 + i]  = off;
        off += local[i];
    }
}

// ---------------- scatter: build inverted index ----------------
__global__ void k_scatter(const int* __restrict__ labels, int* __restrict__ cursor,
                          int* __restrict__ rowidx) {
    int m = blockIdx.x * 256 + threadIdx.x;
    int c = labels[m];
    int p = atomicAdd(&cursor[c], 1);
    rowidx[p] = m;
}

// ---------------- per-class feature mean, scaled by 1/(T*n), to bf16 ----------------
__global__ __launch_bounds__(256) void k_class_mean(const float* __restrict__ feat,
                                                    const int* __restrict__ rowidx,
                                                    const int* __restrict__ offsets,
                                                    const int* __restrict__ counts,
                                                    unsigned short* __restrict__ G) {
    int c = blockIdx.x;
    int n = counts[c];
    int off = offsets[c];
    int t = threadIdx.x;
    float a0=0,a1=0,a2=0,a3=0,b0=0,b1=0,b2=0,b3=0;
    for (int i = 0; i < n; ++i) {
        const float4* row = (const float4*)(feat + (size_t)rowidx[off + i] * D_DIM);
        float4 x = row[t];        // cols 4t .. 4t+3
        float4 y = row[256 + t];  // cols 1024+4t ..
        a0 += x.x; a1 += x.y; a2 += x.z; a3 += x.w;
        b0 += y.x; b1 += y.y; b2 += y.z; b3 += y.w;
    }
    float s = (n > 0) ? (TEMP_INV / (float)n) : 0.0f;
    ushort4 u0 = make_ushort4(f2bf(a0*s), f2bf(a1*s), f2bf(a2*s), f2bf(a3*s));
    ushort4 u1 = make_ushort4(f2bf(b0*s), f2bf(b1*s), f2bf(b2*s), f2bf(b3*s));
    *(ushort4*)(G + (size_t)c * D_DIM + 4*t)        = u0;
    *(ushort4*)(G + (size_t)c * D_DIM + 1024 + 4*t) = u1;
}

// ---------------- L2-normalize inputs, to bf16 ----------------
__global__ __launch_bounds__(256) void k_norm_inputs(const float* __restrict__ inp,
                                                     unsigned short* __restrict__ X) {
    int b = blockIdx.x, t = threadIdx.x;
    const float4* row = (const float4*)(inp + (size_t)b * D_DIM);
    float4 x = row[t], y = row[256 + t];
    float ss = x.x*x.x + x.y*x.y + x.z*x.z + x.w*x.w
             + y.x*y.x + y.y*y.y + y.z*y.z + y.w*y.w;
    for (int o = 32; o > 0; o >>= 1) ss += __shfl_down(ss, o);
    __shared__ float wsum[4];
    if ((t & 63) == 0) wsum[t >> 6] = ss;
    __syncthreads();
    float inv = rsqrtf(wsum[0] + wsum[1] + wsum[2] + wsum[3]);
    ushort4 u0 = make_ushort4(f2bf(x.x*inv), f2bf(x.y*inv), f2bf(x.z*inv), f2bf(x.w*inv));
    ushort4 u1 = make_ushort4(f2bf(y.x*inv), f2bf(y.y*inv), f2bf(y.z*inv), f2bf(y.w*inv));
    *(ushort4*)(X + (size_t)b * D_DIM + 4*t)        = u0;
    *(ushort4*)(X + (size_t)b * D_DIM + 1024 + 4*t) = u1;
}

// ---------------- sim[256, 8192] = Xb16 @ Gb16^T (bf16 MFMA, fp32 accum) ----------------
#define GBM 128
#define GBN 128
#define GBK 32
#define LSTR 40   // padded LDS stride (bf16 elems) to spread banks

__global__ __launch_bounds__(256) void k_gemm(const unsigned short* __restrict__ X,
                                              const unsigned short* __restrict__ G,
                                              float* __restrict__ sim) {
    __shared__ __align__(16) unsigned short As[GBM * LSTR];
    __shared__ __align__(16) unsigned short Bs[GBN * LSTR];
    int tid = threadIdx.x;
    int bc0 = blockIdx.x * GBN;   // class tile
    int br0 = blockIdx.y * GBM;   // batch-row tile
    int lane = tid & 63, wave = tid >> 6;
    int wm = wave >> 1, wn = wave & 1;
    int fr = lane & 15, fk = (lane >> 4) * 8;

    f32x4 acc[4][4];
    #pragma unroll
    for (int i = 0; i < 4; ++i)
        #pragma unroll
        for (int j = 0; j < 4; ++j) acc[i][j] = (f32x4){0.f, 0.f, 0.f, 0.f};

    for (int k0 = 0; k0 < D_DIM; k0 += GBK) {
        #pragma unroll
        for (int it = 0; it < 2; ++it) {
            int e = tid + it * 256;        // 512 groups of 8 bf16
            int row = e >> 2;              // 0..127
            int col = (e & 3) * 8;         // 0,8,16,24
            uint4 va = *(const uint4*)(X + (size_t)(br0 + row) * D_DIM + k0 + col);
            *(uint4*)(As + row * LSTR + col) = va;
            uint4 vb = *(const uint4*)(G + (size_t)(bc0 + row) * D_DIM + k0 + col);
            *(uint4*)(Bs + row * LSTR + col) = vb;
        }
        __syncthreads();
        short8 af[4], bg[4];
        #pragma unroll
        for (int mi = 0; mi < 4; ++mi)
            af[mi] = *(const short8*)(As + (wm*64 + mi*16 + fr) * LSTR + fk);
        #pragma unroll
        for (int ni = 0; ni < 4; ++ni)
            bg[ni] = *(const short8*)(Bs + (wn*64 + ni*16 + fr) * LSTR + fk);
        #pragma unroll
        for (int mi = 0; mi < 4; ++mi)
            #pragma unroll
            for (int ni = 0; ni < 4; ++ni)
                acc[mi][ni] = __builtin_amdgcn_mfma_f32_16x16x32_bf16(af[mi], bg[ni], acc[mi][ni], 0, 0, 0);
        __syncthreads();
    }

    #pragma unroll
    for (int mi = 0; mi < 4; ++mi) {
        int row = br0 + wm*64 + mi*16 + (lane >> 4) * 4;
        #pragma unroll
        for (int ni = 0; ni < 4; ++ni) {
            int col = bc0 + wn*64 + ni*16 + fr;
            #pragma unroll
            for (int r = 0; r < 4; ++r)
                sim[(size_t)(row + r) * C_CLASSES + col] = acc[mi][ni][r];
        }
    }
}

// ---------------- masked softmax denom + per-row NLL ----------------
__global__ __launch_bounds__(256) void k_softmax_loss(const float* __restrict__ sim,
                                                      const int* __restrict__ counts,
                                                      const int* __restrict__ labels,
                                                      const int* __restrict__ idx,
                                                      float* __restrict__ rowloss) {
    int b = blockIdx.x, t = threadIdx.x;
    const float* row = sim + (size_t)b * C_CLASSES;
    float s = 0.f;
    for (int j = t; j < C_CLASSES; j += 256) {
        float v = row[j];
        if (counts[j] > 0) s += expf(v);
    }
    for (int o = 32; o > 0; o >>= 1) s += __shfl_down(s, o);
    __shared__ float wsum[4];
    if ((t & 63) == 0) wsum[t >> 6] = s;
    __syncthreads();
    if (t == 0) {
        float total = wsum[0] + wsum[1] + wsum[2] + wsum[3];
        int target = labels[idx[b]];                 // target class is never empty
        float p = expf(row[target]) / (total + 1e-6f);
        rowloss[b] = -logf(p + 1e-6f);
    }
}

// ---------------- final mean over 256 row losses ----------------
__global__ __launch_bounds__(256) void k_final(const float* __restrict__ rowloss,
                                               float* __restrict__ out) {
    int t = threadIdx.x;
    float v = rowloss[t];
    for (int o = 32; o > 0; o >>= 1) v += __shfl_down(v, o);
    __shared__ float wsum[4];
    if ((t & 63) == 0) wsum[t >> 6] = v;
    __syncthreads();
    if (t == 0) out[0] = (wsum[0] + wsum[1] + wsum[2] + wsum[3]) * (1.0f / 256.0f);
}

extern "C" void kernel_launch(void* const* d_in, const int* in_sizes, int n_in,
                              void* d_out, int out_size, void* d_ws, size_t ws_size,
                              hipStream_t stream) {
    const float* inputs = (const float*)d_in[0];
    const float* feats  = (const float*)d_in[1];
    const int*   labels = (const int*)d_in[2];
    const int*   idx    = (const int*)d_in[3];
    float* out = (float*)d_out;

    char* p = (char*)d_ws;
    auto alloc = [&](size_t bytes) { char* r = p; p += (bytes + 255) & ~(size_t)255; return r; };
    int* counts   = (int*)alloc((size_t)C_CLASSES * 4);
    int* offsets  = (int*)alloc((size_t)C_CLASSES * 4);
    int* cursor   = (int*)alloc((size_t)C_CLASSES * 4);
    int* rowidx   = (int*)alloc((size_t)M_ROWS * 4);
    float* rowloss = (float*)alloc((size_t)B_ROWS * 4);
    unsigned short* Xb = (unsigned short*)alloc((size_t)B_ROWS * D_DIM * 2);
    unsigned short* Gb = (unsigned short*)alloc((size_t)C_CLASSES * D_DIM * 2);
    float* sim = (float*)alloc((size_t)B_ROWS * C_CLASSES * 4);

    hipMemsetAsync(counts, 0, (size_t)C_CLASSES * 4, stream);
    k_hist<<<M_ROWS / 256, 256, 0, stream>>>(labels, counts);
    k_scan<<<1, 256, 0, stream>>>(counts, offsets, cursor);
    k_scatter<<<M_ROWS / 256, 256, 0, stream>>>(labels, cursor, rowidx);
    k_class_mean<<<C_CLASSES, 256, 0, stream>>>(feats, rowidx, offsets, counts, Gb);
    k_norm_inputs<<<B_ROWS, 256, 0, stream>>>(inputs, Xb);
    k_gemm<<<dim3(C_CLASSES / GBN, B_ROWS / GBM), 256, 0, stream>>>(Xb, Gb, sim);
    k_softmax_loss<<<B_ROWS, 256, 0, stream>>>(sim, counts, labels, idx, rowloss);
    k_final<<<1, 256, 0, stream>>>(rowloss, out);
}

// Round 2
// 159.730 us; speedup vs baseline: 1.3320x; 1.3320x over previous
//
#include <hip/hip_runtime.h>
#include <hip/hip_bf16.h>

#define C_CLASSES 8192
#define M_ROWS    65536
#define B_ROWS    256
#define D_DIM     2048
#define TEMP_INV  20.0f   // 1 / 0.05

typedef __attribute__((ext_vector_type(8))) short short8;   // 8 bf16 (4 VGPRs)
typedef __attribute__((ext_vector_type(4))) float f32x4;    // MFMA accumulator / vec4

static __device__ __forceinline__ unsigned short f2bf(float x) {
    __hip_bfloat16 h = __float2bfloat16(x);
    return *reinterpret_cast<unsigned short*>(&h);
}

// async global->LDS, 16B per lane; LDS dest = wave-uniform base + lane*16
static __device__ __forceinline__ void gload16(const void* g, void* l) {
    __builtin_amdgcn_global_load_lds((const __attribute__((address_space(1))) void*)g,
                                     (__attribute__((address_space(3))) void*)l, 16, 0, 0);
}

// ---------------- histogram of labels + L2-normalize inputs (fused) ----------------
__global__ __launch_bounds__(256) void k_hist_norm(const int* __restrict__ labels,
                                                   int* __restrict__ counts,
                                                   const float* __restrict__ inp,
                                                   unsigned short* __restrict__ X) {
    int b = blockIdx.x, t = threadIdx.x;
    atomicAdd(&counts[labels[b * 256 + t]], 1);

    const f32x4* row = (const f32x4*)(inp + (size_t)b * D_DIM);
    f32x4 x = row[t], y = row[256 + t];
    float ss = x.x*x.x + x.y*x.y + x.z*x.z + x.w*x.w
             + y.x*y.x + y.y*y.y + y.z*y.z + y.w*y.w;
    for (int o = 32; o > 0; o >>= 1) ss += __shfl_down(ss, o);
    __shared__ float wsum[4];
    if ((t & 63) == 0) wsum[t >> 6] = ss;
    __syncthreads();
    float inv = rsqrtf(wsum[0] + wsum[1] + wsum[2] + wsum[3]);
    ushort4 u0 = make_ushort4(f2bf(x.x*inv), f2bf(x.y*inv), f2bf(x.z*inv), f2bf(x.w*inv));
    ushort4 u1 = make_ushort4(f2bf(y.x*inv), f2bf(y.y*inv), f2bf(y.z*inv), f2bf(y.w*inv));
    *(ushort4*)(X + (size_t)b * D_DIM + 4*t)        = u0;
    *(ushort4*)(X + (size_t)b * D_DIM + 1024 + 4*t) = u1;
}

// ---------------- exclusive scan over 8192 counts (1 block) + zero the output ----------------
__global__ __launch_bounds__(256) void k_scan(const int* __restrict__ counts,
                                              int* __restrict__ offsets,
                                              int* __restrict__ cursor,
                                              float* __restrict__ out) {
    __shared__ int part[256];
    int t = threadIdx.x;
    int local[32];
    int s = 0;
    #pragma unroll
    for (int i = 0; i < 32; ++i) { local[i] = counts[t * 32 + i]; s += local[i]; }
    part[t] = s;
    __syncthreads();
    if (t == 0) {
        int acc = 0;
        for (int i = 0; i < 256; ++i) { int v = part[i]; part[i] = acc; acc += v; }
        out[0] = 0.0f;   // k_loss accumulates atomically into this
    }
    __syncthreads();
    int off = part[t];
    #pragma unroll
    for (int i = 0; i < 32; ++i) {
        offsets[t * 32 + i] = off;
        cursor[t * 32 + i]  = off;
        off += local[i];
    }
}

// ---------------- scatter: build inverted index ----------------
__global__ void k_scatter(const int* __restrict__ labels, int* __restrict__ cursor,
                          int* __restrict__ rowidx) {
    int m = blockIdx.x * 256 + threadIdx.x;
    int c = labels[m];
    int p = atomicAdd(&cursor[c], 1);
    rowidx[p] = m;
}

// ---------------- per-class feature mean, scaled by 1/(T*n), to bf16 ----------------
__global__ __launch_bounds__(256) void k_class_mean(const float* __restrict__ feat,
                                                    const int* __restrict__ rowidx,
                                                    const int* __restrict__ offsets,
                                                    const int* __restrict__ counts,
                                                    unsigned short* __restrict__ G) {
    int c = blockIdx.x;
    int n = counts[c];
    int off = offsets[c];
    int t = threadIdx.x;
    f32x4 a = {0.f,0.f,0.f,0.f}, b = {0.f,0.f,0.f,0.f};
    int i = 0;
    for (; i + 1 < n; i += 2) {   // 2 rows in flight for memory-level parallelism
        const f32x4* p0 = (const f32x4*)(feat + (size_t)rowidx[off + i]     * D_DIM);
        const f32x4* p1 = (const f32x4*)(feat + (size_t)rowidx[off + i + 1] * D_DIM);
        f32x4 x0 = __builtin_nontemporal_load(p0 + t);
        f32x4 y0 = __builtin_nontemporal_load(p0 + 256 + t);
        f32x4 x1 = __builtin_nontemporal_load(p1 + t);
        f32x4 y1 = __builtin_nontemporal_load(p1 + 256 + t);
        a += x0 + x1;
        b += y0 + y1;
    }
    if (i < n) {
        const f32x4* p0 = (const f32x4*)(feat + (size_t)rowidx[off + i] * D_DIM);
        a += __builtin_nontemporal_load(p0 + t);
        b += __builtin_nontemporal_load(p0 + 256 + t);
    }
    float s = (n > 0) ? (TEMP_INV / (float)n) : 0.0f;
    a *= s; b *= s;
    ushort4 u0 = make_ushort4(f2bf(a.x), f2bf(a.y), f2bf(a.z), f2bf(a.w));
    ushort4 u1 = make_ushort4(f2bf(b.x), f2bf(b.y), f2bf(b.z), f2bf(b.w));
    *(ushort4*)(G + (size_t)c * D_DIM + 4*t)        = u0;
    *(ushort4*)(G + (size_t)c * D_DIM + 1024 + 4*t) = u1;
}

// ---------------- sim[256, 8192] = X @ G^T (bf16 MFMA, fp32 accum) ----------------
// 64x64 tile, BK=64, 512 blocks (2/CU), global_load_lds w=16 with pre-swizzled
// source (both-sides XOR swizzle), LDS double-buffer, stage-before-MFMA.
__global__ __launch_bounds__(256) void k_gemm(const unsigned short* __restrict__ X,
                                              const unsigned short* __restrict__ G,
                                              float* __restrict__ sim) {
    __shared__ unsigned short As[2][64 * 64];
    __shared__ unsigned short Bs[2][64 * 64];
    int tid = threadIdx.x;
    int bid = blockIdx.x;                       // 0..511
    int swz = (bid & 7) * 64 + (bid >> 3);      // XCD-chunked (512 % 8 == 0, bijective)
    int ct = swz >> 2, rt = swz & 3;
    int bc0 = ct * 64;                          // class tile base
    int br0 = rt * 64;                          // batch-row tile base

    int lane = tid & 63, wave = tid >> 6;
    int wm = wave >> 1, wn = wave & 1;          // 2x2 wave grid, 32x32 per wave
    int fr = lane & 15;
    int fkb = (lane >> 4) << 4;                 // byte offset of 8-elem k-fragment
    int rowl = lane >> 3;                       // 0..7: row within 1KB lane-block
    int colsw = ((lane & 7) ^ rowl) << 3;       // pre-swizzled source col (elems)

    f32x4 acc[2][2];
    #pragma unroll
    for (int i = 0; i < 2; ++i)
        #pragma unroll
        for (int j = 0; j < 2; ++j) acc[i][j] = (f32x4){0.f, 0.f, 0.f, 0.f};

    // stage one 64x64 K-tile of A and B into LDS buffer `buf` (async)
    auto stage = [&](int buf, int k0) {
        #pragma unroll
        for (int it = 0; it < 2; ++it) {
            int row = wave * 8 + it * 32 + rowl;
            gload16(X + (size_t)(br0 + row) * D_DIM + k0 + colsw,
                    &As[buf][wave * 512 + it * 2048]);
            gload16(G + (size_t)(bc0 + row) * D_DIM + k0 + colsw,
                    &Bs[buf][wave * 512 + it * 2048]);
        }
    };

    stage(0, 0);
    int cur = 0;
    const int NT = D_DIM / 64;   // 32
    for (int t = 0; t < NT; ++t) {
        asm volatile("s_waitcnt vmcnt(0)" ::: "memory");
        __syncthreads();                         // buf[cur] ready for all waves
        if (t + 1 < NT) stage(cur ^ 1, (t + 1) * 64);   // prefetch overlaps MFMA

        short8 af[2][2], bg[2][2];
        #pragma unroll
        for (int kk = 0; kk < 2; ++kk) {
            int cb = (kk * 64 + fkb) ^ ((fr & 7) << 4);   // swizzled byte col
            #pragma unroll
            for (int mi = 0; mi < 2; ++mi) {
                int row = wm * 32 + mi * 16 + fr;
                af[mi][kk] = *(const short8*)((const char*)As[cur] + row * 128 + cb);
            }
            #pragma unroll
            for (int ni = 0; ni < 2; ++ni) {
                int row = wn * 32 + ni * 16 + fr;
                bg[ni][kk] = *(const short8*)((const char*)Bs[cur] + row * 128 + cb);
            }
        }
        #pragma unroll
        for (int kk = 0; kk < 2; ++kk)
            #pragma unroll
            for (int mi = 0; mi < 2; ++mi)
                #pragma unroll
                for (int ni = 0; ni < 2; ++ni)
                    acc[mi][ni] = __builtin_amdgcn_mfma_f32_16x16x32_bf16(
                        af[mi][kk], bg[ni][kk], acc[mi][ni], 0, 0, 0);
        cur ^= 1;
    }

    #pragma unroll
    for (int mi = 0; mi < 2; ++mi) {
        int row = br0 + wm * 32 + mi * 16 + (lane >> 4) * 4;
        #pragma unroll
        for (int ni = 0; ni < 2; ++ni) {
            int col = bc0 + wn * 32 + ni * 16 + fr;
            #pragma unroll
            for (int r = 0; r < 4; ++r)
                sim[(size_t)(row + r) * C_CLASSES + col] = acc[mi][ni][r];
        }
    }
}

// ---------------- masked softmax denom + NLL, one atomicAdd per row ----------------
__global__ __launch_bounds__(256) void k_loss(const float* __restrict__ sim,
                                              const int* __restrict__ counts,
                                              const int* __restrict__ labels,
                                              const int* __restrict__ idx,
                                              float* __restrict__ out) {
    int b = blockIdx.x, t = threadIdx.x;
    const float* row = sim + (size_t)b * C_CLASSES;
    const f32x4* row4 = (const f32x4*)row;
    const int4*  cnt4 = (const int4*)counts;
    float s = 0.f;
    for (int j = t; j < C_CLASSES / 4; j += 256) {
        f32x4 v = row4[j];
        int4  c = cnt4[j];
        if (c.x > 0) s += expf(v.x);
        if (c.y > 0) s += expf(v.y);
        if (c.z > 0) s += expf(v.z);
        if (c.w > 0) s += expf(v.w);
    }
    for (int o = 32; o > 0; o >>= 1) s += __shfl_down(s, o);
    __shared__ float wsum[4];
    if ((t & 63) == 0) wsum[t >> 6] = s;
    __syncthreads();
    if (t == 0) {
        float total = wsum[0] + wsum[1] + wsum[2] + wsum[3];
        int target = labels[idx[b]];                 // target class is never empty
        float p = expf(row[target]) / (total + 1e-6f);
        atomicAdd(out, -logf(p + 1e-6f) * (1.0f / 256.0f));
    }
}

extern "C" void kernel_launch(void* const* d_in, const int* in_sizes, int n_in,
                              void* d_out, int out_size, void* d_ws, size_t ws_size,
                              hipStream_t stream) {
    const float* inputs = (const float*)d_in[0];
    const float* feats  = (const float*)d_in[1];
    const int*   labels = (const int*)d_in[2];
    const int*   idx    = (const int*)d_in[3];
    float* out = (float*)d_out;

    char* p = (char*)d_ws;
    auto alloc = [&](size_t bytes) { char* r = p; p += (bytes + 255) & ~(size_t)255; return r; };
    int* counts   = (int*)alloc((size_t)C_CLASSES * 4);
    int* offsets  = (int*)alloc((size_t)C_CLASSES * 4);
    int* cursor   = (int*)alloc((size_t)C_CLASSES * 4);
    int* rowidx   = (int*)alloc((size_t)M_ROWS * 4);
    unsigned short* Xb = (unsigned short*)alloc((size_t)B_ROWS * D_DIM * 2);
    unsigned short* Gb = (unsigned short*)alloc((size_t)C_CLASSES * D_DIM * 2);
    float* sim = (float*)alloc((size_t)B_ROWS * C_CLASSES * 4);

    hipMemsetAsync(counts, 0, (size_t)C_CLASSES * 4, stream);
    k_hist_norm<<<B_ROWS, 256, 0, stream>>>(labels, counts, inputs, Xb);
    k_scan<<<1, 256, 0, stream>>>(counts, offsets, cursor, out);
    k_scatter<<<M_ROWS / 256, 256, 0, stream>>>(labels, cursor, rowidx);
    k_class_mean<<<C_CLASSES, 256, 0, stream>>>(feats, rowidx, offsets, counts, Gb);
    k_gemm<<<512, 256, 0, stream>>>(Xb, Gb, sim);
    k_loss<<<B_ROWS, 256, 0, stream>>>(sim, counts, labels, idx, out);
}